// Round 7
// baseline (274.979 us; speedup 1.0000x reference)
//
#include <hip/hip_runtime.h>

#define NS 8192
#define EMBED 128
#define COLCHUNK 1024            // grid.y = 8 chunks of 1024 cols
#define NPH (COLCHUNK / 32)      // 32 phases of 32 cols
#define AROW 12                  // adj-hist row stride (11 bins + 1 pad)
#define INV64K (1.0f / 65536.0f)

typedef __bf16 bf16x8 __attribute__((ext_vector_type(8)));
typedef float f32x4 __attribute__((ext_vector_type(4)));
typedef const __attribute__((address_space(1))) unsigned ag_u32;  // global
typedef __attribute__((address_space(3))) unsigned al_u32;        // LDS

// raw barrier + manual vmcnt: drain all but the IMM newest vmem ops, then
// s_barrier WITHOUT the __syncthreads vmcnt(0) drain (AITER-style pipeline).
// gfx9 s_waitcnt imm: lgkmcnt[11:8]=15, expcnt[6:4]=7, vmcnt[3:0]=N.
#define SYNCV(imm) do {                       \
    __builtin_amdgcn_sched_barrier(0);        \
    __builtin_amdgcn_s_waitcnt(imm);          \
    __builtin_amdgcn_s_barrier();             \
    __builtin_amdgcn_sched_barrier(0);        \
  } while (0)
#define WAIT_VM2 0xF72
#define WAIT_VM0 0xF70

// workspace layout (bytes from ws start)
#define OFF_XB  0u               // bf16 [8192][128] = 2 MiB (row-granule-XOR-swizzled)
#define OFF_GS  2097152u         // fp32 [8192][4]   cumulative C bins 3..6
#define OFF_GSP 2228224u         // fp32 [8192][4]   cumulative Cp bins 3..6
#define OFF_GA  2359296u         // i32  [8192][12]  all-hist corrections (q16)
#define OFF_GAP 2752512u         // i32  [8192][12]  pos-hist corrections (q16)
#define OFF_CC  3145728u         // int  [128] class counts
#define OFF_AC  3146240u         // float[2] accum + u32 done
#define ZERO_BYTES 1049120u      // OFF_GS .. end (16B multiple)

__device__ inline unsigned short f2bf(float f) {
  unsigned u = __float_as_uint(f);
  u += 0x7fffu + ((u >> 16) & 1u);   // round-to-nearest-even
  return (unsigned short)(u >> 16);
}
__device__ inline float clamp01(float x) { return fminf(fmaxf(x, 0.f), 1.f); }

// ---- prep: fp32->bf16 convert into XOR-swizzled layout + zero accumulators ----
// Row r's sixteen 16B granules are stored at physical slot g^(r&7), so the main
// kernel's LINEAR global_load_lds staging still gives low-conflict ds_read_b128.
__global__ __launch_bounds__(256) void prep_kernel(const float* __restrict__ x,
                                                   unsigned short* __restrict__ xb,
                                                   uint4* __restrict__ zbase) {
  const int gid = blockIdx.x * 256 + threadIdx.x;   // 131072 threads: row*16+granule
  const int row = gid >> 4, g = gid & 15;
  const float4 v0 = reinterpret_cast<const float4*>(x)[row * 32 + g * 2];
  const float4 v1 = reinterpret_cast<const float4*>(x)[row * 32 + g * 2 + 1];
  uint4 o;
  o.x = (unsigned)f2bf(v0.x) | ((unsigned)f2bf(v0.y) << 16);
  o.y = (unsigned)f2bf(v0.z) | ((unsigned)f2bf(v0.w) << 16);
  o.z = (unsigned)f2bf(v1.x) | ((unsigned)f2bf(v1.y) << 16);
  o.w = (unsigned)f2bf(v1.z) | ((unsigned)f2bf(v1.w) << 16);
  reinterpret_cast<uint4*>(xb)[row * 16 + (g ^ (row & 7))] = o;
  if (gid < (int)(ZERO_BYTES / 16u)) zbase[gid] = make_uint4(0u, 0u, 0u, 0u);
}

// ---- main: triple-buffered async B staging, raw-barrier pipeline ----
__global__ __launch_bounds__(256, 4) void fastap_main_kernel(
    const unsigned short* __restrict__ xb,
    const int* __restrict__ labels,
    float* __restrict__ gS, float* __restrict__ gSp,
    unsigned* __restrict__ gA, unsigned* __restrict__ gAp,
    int* __restrict__ ccount) {
  __shared__ __align__(16) unsigned short sB[3][32 * 128];  // 3 x 8KB panels
  __shared__ int sLab[COLCHUNK];
  __shared__ unsigned sHs[64 * AROW];   // all-hist corrections (signed q16)
  __shared__ unsigned sHsp[64 * AROW];  // pos-hist corrections (signed q16)

  const int tid  = threadIdx.x;
  const int wave = tid >> 6;
  const int lane = tid & 63;
  const int l16  = lane & 15;
  const int quad = lane >> 4;
  const int rowBase  = blockIdx.x * 64;
  const int colBegin = blockIdx.y * COLCHUNK;
  const int rl0 = wave * 16 + quad * 4;

  if (blockIdx.y == 0 && tid < 64) atomicAdd(&ccount[labels[rowBase + tid]], 1);

  reinterpret_cast<int4*>(sLab)[tid] =
      reinterpret_cast<const int4*>(labels + colBegin)[tid];
  for (int i = tid; i < 64 * AROW; i += 256) { sHs[i] = 0u; sHsp[i] = 0u; }

  // A fragments from swizzled xb: logical granule kb*4+quad at phys ^(arow&7)
  bf16x8 afr[4];
  const int arow = rowBase + wave * 16 + l16;
  #pragma unroll
  for (int kb = 0; kb < 4; ++kb) {
    const int pg = (kb * 4 + quad) ^ (arow & 7);
    afr[kb] = *reinterpret_cast<const bf16x8*>(&xb[arow * 128 + pg * 8]);
  }

  int labi[4], iRow[4];
  #pragma unroll
  for (int r = 0; r < 4; ++r) {
    iRow[r] = rowBase + rl0 + r;
    labi[r] = labels[iRow[r]];
  }

  float C[4][4], Cp[4][4];
  #pragma unroll
  for (int r = 0; r < 4; ++r)
    #pragma unroll
    for (int k = 0; k < 4; ++k) { C[r][k] = 0.f; Cp[r][k] = 0.f; }

  // ds_read offsets (ushort units) within a 16-col sub-panel; (ct+l16)&7==l16&7
  int bOff[4];
  #pragma unroll
  for (int kb = 0; kb < 4; ++kb)
    bOff[kb] = l16 * 128 + (((kb * 4 + quad) ^ (l16 & 7)) << 3);

  // stage phase ph's 32-col panel (8KB) into buffer b: 2 x 16B per thread
  const unsigned short* xcb = xb + colBegin * 128;
  auto stage = [&](int ph, int b) {
    const unsigned short* src = xcb + ph * (32 * 128);
    __builtin_amdgcn_global_load_lds((ag_u32*)(src + tid * 8),
                                     (al_u32*)(&sB[b][tid * 8]), 16, 0, 0);
    __builtin_amdgcn_global_load_lds((ag_u32*)(src + (tid + 256) * 8),
                                     (al_u32*)(&sB[b][(tid + 256) * 8]), 16, 0, 0);
  };

  // compute one 16-col sub-tile at chunk-offset c0 from sub-panel bp
  auto tile16 = [&](const unsigned short* bp, int c0) {
    const int labj = sLab[c0 + l16];
    const int j = colBegin + c0 + l16;           // C/D: col = lane&15
    const bf16x8 b0 = *reinterpret_cast<const bf16x8*>(&bp[bOff[0]]);
    const bf16x8 b1 = *reinterpret_cast<const bf16x8*>(&bp[bOff[1]]);
    const bf16x8 b2 = *reinterpret_cast<const bf16x8*>(&bp[bOff[2]]);
    const bf16x8 b3 = *reinterpret_cast<const bf16x8*>(&bp[bOff[3]]);
    f32x4 acc0 = {0.f, 0.f, 0.f, 0.f}, acc1 = {0.f, 0.f, 0.f, 0.f};
    acc0 = __builtin_amdgcn_mfma_f32_16x16x32_bf16(afr[0], b0, acc0, 0, 0, 0);
    acc0 = __builtin_amdgcn_mfma_f32_16x16x32_bf16(afr[1], b1, acc0, 0, 0, 0);
    acc1 = __builtin_amdgcn_mfma_f32_16x16x32_bf16(afr[2], b2, acc1, 0, 0, 0);
    acc1 = __builtin_amdgcn_mfma_f32_16x16x32_bf16(afr[3], b3, acc1, 0, 0, 0);

    #pragma unroll
    for (int r = 0; r < 4; ++r) {                // C/D: row = quad*4 + reg
      const float a = acc0[r] + acc1[r];         // cos;  u = t-5 = -5a
      const bool isPos = (labi[r] == labj) & (iRow[r] != j);
      const float pm = isPos ? 1.f : 0.f;
      const float d0 = clamp01(fmaf(a, 5.f, -1.f));   // bin 3
      const float d1 = clamp01(a * 5.f);              // bin 4
      const float d2 = clamp01(fmaf(a, 5.f, 1.f));    // bin 5
      const float d3 = clamp01(fmaf(a, 5.f, 2.f));    // bin 6
      C[r][0] += d0; C[r][1] += d1; C[r][2] += d2; C[r][3] += d3;
      Cp[r][0] = fmaf(pm, d0, Cp[r][0]);
      Cp[r][1] = fmaf(pm, d1, Cp[r][1]);
      Cp[r][2] = fmaf(pm, d2, Cp[r][2]);
      Cp[r][3] = fmaf(pm, d3, Cp[r][3]);

      if (fabsf(a) > 0.4f) {                     // rare: outlier or diagonal
        const int row = rl0 + r;
        if (iRow[r] == j) {
          C[r][0] -= d0; C[r][1] -= d1; C[r][2] -= d2; C[r][3] -= d3;
          #pragma unroll
          for (int k = 7; k <= 10; ++k)
            atomicAdd(&sHs[row * AROW + k], (unsigned)(-65536));
        } else {
          const float t = fmaf(a, -5.f, 5.f);
          #pragma unroll
          for (int k = 0; k <= 2; ++k) {         // assumed cumulative 0
            const float v = clamp01((float)(k + 1) - t);
            const int q = (int)(v * 65536.f + 0.5f);
            if (q) {
              atomicAdd(&sHs[row * AROW + k], (unsigned)q);
              if (isPos) atomicAdd(&sHsp[row * AROW + k], (unsigned)q);
            }
          }
          #pragma unroll
          for (int k = 7; k <= 10; ++k) {        // assumed cumulative 1
            const float v = clamp01((float)(k + 1) - t) - 1.f;
            const int q = (int)(v * 65536.f - 0.5f);
            if (q) {
              atomicAdd(&sHs[row * AROW + k], (unsigned)q);
              if (isPos) atomicAdd(&sHsp[row * AROW + k], (unsigned)q);
            }
          }
        }
      }
    }
  };

  __syncthreads();           // sLab/sHs init visible; full drain (once)
  stage(0, 0);
  stage(1, 1);

  // 30 pipelined phases (unroll x3 -> static buffer indices), distance-2
  // prefetch, vmcnt(2) = "all but newest panel's 2 loads done".
  int ph = 0;
  #pragma unroll 1
  for (int it = 0; it < 10; ++it) {
    SYNCV(WAIT_VM2); stage(ph + 2, 2);
    tile16(&sB[0][0], ph * 32); tile16(&sB[0][16 * 128], ph * 32 + 16);
    SYNCV(WAIT_VM2); stage(ph + 3, 0);
    tile16(&sB[1][0], ph * 32 + 32); tile16(&sB[1][16 * 128], ph * 32 + 48);
    SYNCV(WAIT_VM2); stage(ph + 4, 1);
    tile16(&sB[2][0], ph * 32 + 64); tile16(&sB[2][16 * 128], ph * 32 + 80);
    ph += 3;
  }
  // tail: phases 30 (buf0) and 31 (buf1), no more prefetch
  SYNCV(WAIT_VM2);
  tile16(&sB[0][0], 30 * 32); tile16(&sB[0][16 * 128], 30 * 32 + 16);
  SYNCV(WAIT_VM0);
  tile16(&sB[1][0], 31 * 32); tile16(&sB[1][16 * 128], 31 * 32 + 16);

  // butterfly-reduce C/Cp across the 16 lanes sharing each row
  #pragma unroll
  for (int m = 1; m < 16; m <<= 1)
    #pragma unroll
    for (int r = 0; r < 4; ++r)
      #pragma unroll
      for (int k = 0; k < 4; ++k) {
        C[r][k]  += __shfl_xor(C[r][k],  m, 64);
        Cp[r][k] += __shfl_xor(Cp[r][k], m, 64);
      }

  if (l16 == 0) {
    #pragma unroll
    for (int r = 0; r < 4; ++r)
      #pragma unroll
      for (int k = 0; k < 4; ++k) {
        atomicAdd(&gS[(rowBase + rl0 + r) * 4 + k],  C[r][k]);
        atomicAdd(&gSp[(rowBase + rl0 + r) * 4 + k], Cp[r][k]);
      }
  }

  __syncthreads();           // full drain: sHs/sHsp atomics complete
  for (int idx = tid; idx < 64 * AROW; idx += 256) {
    const unsigned v = sHs[idx], vp = sHsp[idx];
    if (v)  atomicAdd(&gA[rowBase * AROW + idx], v);
    if (vp) atomicAdd(&gAp[rowBase * AROW + idx], vp);
  }
}

// ---- epilogue: per-row AP + final loss (last block finalizes) ----
__global__ __launch_bounds__(256) void epilogue_kernel(
    const float* __restrict__ gS, const float* __restrict__ gSp,
    const unsigned* __restrict__ gA, const unsigned* __restrict__ gAp,
    const int* __restrict__ labels, const int* __restrict__ ccount,
    float* __restrict__ accum, unsigned* __restrict__ done,
    float* __restrict__ out) {
  const int i = blockIdx.x * 256 + threadIdx.x;
  const int np = ccount[labels[i]] - 1;   // N_pos = classCount - 1
  float ap = 0.f, val = 0.f, HpPrev = 0.f;
  #pragma unroll
  for (int b = 0; b <= 10; ++b) {
    const float baseH  = (b < 3) ? 0.f : (b < 7) ? gS[i * 4 + (b - 3)]  : 8192.f;
    const float basePp = (b < 3) ? 0.f : (b < 7) ? gSp[i * 4 + (b - 3)] : (float)np;
    const float H  = baseH  + (float)(int)gA[i * AROW + b]  * INV64K;
    const float Hp = basePp + (float)(int)gAp[i * AROW + b] * INV64K;
    const float hp = Hp - HpPrev;
    HpPrev = Hp;
    if (H > 1e-6f) ap += hp * Hp / H;
  }
  if (np > 0) { ap /= (float)np; val = 1.f; } else ap = 0.f;

  __shared__ float sa[256], sv[256];
  sa[threadIdx.x] = ap; sv[threadIdx.x] = val;
  __syncthreads();
  for (int s = 128; s > 0; s >>= 1) {
    if (threadIdx.x < s) {
      sa[threadIdx.x] += sa[threadIdx.x + s];
      sv[threadIdx.x] += sv[threadIdx.x + s];
    }
    __syncthreads();
  }
  if (threadIdx.x == 0) {
    atomicAdd(&accum[0], sa[0]);
    atomicAdd(&accum[1], sv[0]);
    __threadfence();
    const unsigned prev = atomicAdd(done, 1u);
    if (prev == gridDim.x - 1) {
      const float a = atomicAdd(&accum[0], 0.f);   // coherent reads
      const float c = atomicAdd(&accum[1], 0.f);
      out[0] = 1.f - (c > 0.f ? a / c : 0.f);
    }
  }
}

extern "C" void kernel_launch(void* const* d_in, const int* in_sizes, int n_in,
                              void* d_out, int out_size, void* d_ws, size_t ws_size,
                              hipStream_t stream) {
  const float* x      = (const float*)d_in[0];
  const int*   labels = (const int*)d_in[1];
  float* out = (float*)d_out;

  char* ws = (char*)d_ws;
  unsigned short* xb = (unsigned short*)(ws + OFF_XB);
  float*    gS   = (float*)(ws + OFF_GS);
  float*    gSp  = (float*)(ws + OFF_GSP);
  unsigned* gA   = (unsigned*)(ws + OFF_GA);
  unsigned* gAp  = (unsigned*)(ws + OFF_GAP);
  int*      cc   = (int*)(ws + OFF_CC);
  float*    accum = (float*)(ws + OFF_AC);
  unsigned* done  = (unsigned*)(ws + OFF_AC + 8);

  prep_kernel<<<512, 256, 0, stream>>>(x, xb, (uint4*)(ws + OFF_GS));
  fastap_main_kernel<<<dim3(NS / 64, NS / COLCHUNK), 256, 0, stream>>>(
      xb, labels, gS, gSp, gA, gAp, cc);
  epilogue_kernel<<<NS / 256, 256, 0, stream>>>(gS, gSp, gA, gAp, labels, cc,
                                                accum, done, out);
}

// Round 8
// 152.748 us; speedup vs baseline: 1.8002x; 1.8002x over previous
//
#include <hip/hip_runtime.h>

#define NS 8192
#define EMBED 128
#define COLCHUNK 1024            // grid.y = 8 chunks of 1024 cols
#define NPH (COLCHUNK / 64)      // 16 phases of 64 cols
#define AROW 12                  // correction-hist row stride (11 bins + 1 pad)
#define INV64K (1.0f / 65536.0f)

typedef __bf16 bf16x8 __attribute__((ext_vector_type(8)));
typedef float f32x4 __attribute__((ext_vector_type(4)));
typedef const __attribute__((address_space(1))) unsigned ag_u32;  // global
typedef __attribute__((address_space(3))) unsigned al_u32;        // LDS

// workspace layout (bytes from ws start)
#define OFF_XB  0u               // bf16 [8192][128] = 2 MiB (row-granule-XOR-swizzled)
#define OFF_GS  2097152u         // fp32 [8192][4]   cumulative C bins 3..6
#define OFF_GSP 2228224u         // fp32 [8192][4]   cumulative Cp bins 3..6
#define OFF_GA  2359296u         // i32  [8192][12]  all-hist corrections (q16)
#define OFF_GAP 2752512u         // i32  [8192][12]  pos-hist corrections (q16)
#define OFF_CC  3145728u         // int  [128] class counts
#define OFF_AC  3146240u         // float[2] accum + u32 done
#define ZERO_BYTES 1049120u      // OFF_GS .. end (16B multiple)

__device__ inline unsigned short f2bf(float f) {
  unsigned u = __float_as_uint(f);
  u += 0x7fffu + ((u >> 16) & 1u);   // round-to-nearest-even
  return (unsigned short)(u >> 16);
}
__device__ inline float clamp01(float x) { return __builtin_amdgcn_fmed3f(x, 0.f, 1.f); }

// ---- prep: fp32->bf16 convert into XOR-swizzled layout + zero accumulators ----
// Row r's sixteen 16B granules are stored at physical slot g^(r&7), so the main
// kernel's LINEAR global_load_lds staging still gives low-conflict ds_read_b128.
__global__ __launch_bounds__(256) void prep_kernel(const float* __restrict__ x,
                                                   unsigned short* __restrict__ xb,
                                                   uint4* __restrict__ zbase) {
  const int gid = blockIdx.x * 256 + threadIdx.x;   // 131072 threads: row*16+granule
  const int row = gid >> 4, g = gid & 15;
  const float4 v0 = reinterpret_cast<const float4*>(x)[row * 32 + g * 2];
  const float4 v1 = reinterpret_cast<const float4*>(x)[row * 32 + g * 2 + 1];
  uint4 o;
  o.x = (unsigned)f2bf(v0.x) | ((unsigned)f2bf(v0.y) << 16);
  o.y = (unsigned)f2bf(v0.z) | ((unsigned)f2bf(v0.w) << 16);
  o.z = (unsigned)f2bf(v1.x) | ((unsigned)f2bf(v1.y) << 16);
  o.w = (unsigned)f2bf(v1.z) | ((unsigned)f2bf(v1.w) << 16);
  reinterpret_cast<uint4*>(xb)[row * 16 + (g ^ (row & 7))] = o;
  if (gid < (int)(ZERO_BYTES / 16u)) zbase[gid] = make_uint4(0u, 0u, 0u, 0u);
}

// ---- main: 64-col double-buffered async B staging + MFMA + register hist ----
__global__ __launch_bounds__(256, 4) void fastap_main_kernel(
    const unsigned short* __restrict__ xb,
    const int* __restrict__ labels,
    float* __restrict__ gS, float* __restrict__ gSp,
    unsigned* __restrict__ gA, unsigned* __restrict__ gAp,
    int* __restrict__ ccount) {
  __shared__ __align__(16) unsigned short sB[2][64 * 128];  // 2 x 16KB panels
  __shared__ int sLab[COLCHUNK];

  const int tid  = threadIdx.x;
  const int wave = tid >> 6;
  const int lane = tid & 63;
  const int l16  = lane & 15;
  const int quad = lane >> 4;
  const int rowBase  = blockIdx.x * 64;
  const int colBegin = blockIdx.y * COLCHUNK;
  const int rl0 = wave * 16 + quad * 4;

  if (blockIdx.y == 0 && tid < 64) atomicAdd(&ccount[labels[rowBase + tid]], 1);

  reinterpret_cast<int4*>(sLab)[tid] =
      reinterpret_cast<const int4*>(labels + colBegin)[tid];

  // A fragments from swizzled xb: logical granule kb*4+quad at phys ^(arow&7)
  bf16x8 afr[4];
  const int arow = rowBase + wave * 16 + l16;
  #pragma unroll
  for (int kb = 0; kb < 4; ++kb) {
    const int pg = (kb * 4 + quad) ^ (arow & 7);
    afr[kb] = *reinterpret_cast<const bf16x8*>(&xb[arow * 128 + pg * 8]);
  }

  int labi[4], iRow[4];
  #pragma unroll
  for (int r = 0; r < 4; ++r) {
    iRow[r] = rowBase + rl0 + r;
    labi[r] = labels[iRow[r]];
  }

  float C[4][4], Cp[4][4];
  #pragma unroll
  for (int r = 0; r < 4; ++r)
    #pragma unroll
    for (int k = 0; k < 4; ++k) { C[r][k] = 0.f; Cp[r][k] = 0.f; }

  // ds_read offsets (ushort units) within a 16-col sub-panel; (ct+l16)&7==l16&7
  int bOff[4];
  #pragma unroll
  for (int kb = 0; kb < 4; ++kb)
    bOff[kb] = l16 * 128 + (((kb * 4 + quad) ^ (l16 & 7)) << 3);

  // stage phase ph's 64-col panel (16KB) into buffer b: 4 x 16B per thread
  const unsigned short* xcb = xb + colBegin * 128;
  auto stage = [&](int ph, int b) {
    const unsigned short* src = xcb + ph * (64 * 128);
    #pragma unroll
    for (int i = 0; i < 4; ++i)
      __builtin_amdgcn_global_load_lds(
          (ag_u32*)(src + (tid + i * 256) * 8),
          (al_u32*)(&sB[b][(tid + i * 256) * 8]), 16, 0, 0);
  };

  // compute one 16-col sub-tile at chunk-offset c0 from sub-panel bp
  auto tile16 = [&](const unsigned short* bp, int c0) {
    const int labj = sLab[c0 + l16];
    const int j = colBegin + c0 + l16;           // C/D: col = lane&15
    const bf16x8 b0 = *reinterpret_cast<const bf16x8*>(&bp[bOff[0]]);
    const bf16x8 b1 = *reinterpret_cast<const bf16x8*>(&bp[bOff[1]]);
    const bf16x8 b2 = *reinterpret_cast<const bf16x8*>(&bp[bOff[2]]);
    const bf16x8 b3 = *reinterpret_cast<const bf16x8*>(&bp[bOff[3]]);
    f32x4 acc0 = {0.f, 0.f, 0.f, 0.f}, acc1 = {0.f, 0.f, 0.f, 0.f};
    acc0 = __builtin_amdgcn_mfma_f32_16x16x32_bf16(afr[0], b0, acc0, 0, 0, 0);
    acc0 = __builtin_amdgcn_mfma_f32_16x16x32_bf16(afr[1], b1, acc0, 0, 0, 0);
    acc1 = __builtin_amdgcn_mfma_f32_16x16x32_bf16(afr[2], b2, acc1, 0, 0, 0);
    acc1 = __builtin_amdgcn_mfma_f32_16x16x32_bf16(afr[3], b3, acc1, 0, 0, 0);

    #pragma unroll
    for (int r = 0; r < 4; ++r) {                // C/D: row = quad*4 + reg
      const float a = acc0[r] + acc1[r];         // cos;  u = t-5 = -5a
      const bool isPos = (labi[r] == labj) & (iRow[r] != j);
      const float pm = isPos ? 1.f : 0.f;
      const float d0 = clamp01(fmaf(a, 5.f, -1.f));   // bin 3
      const float d1 = clamp01(a * 5.f);              // bin 4
      const float d2 = clamp01(fmaf(a, 5.f, 1.f));    // bin 5
      const float d3 = clamp01(fmaf(a, 5.f, 2.f));    // bin 6
      C[r][0] += d0; C[r][1] += d1; C[r][2] += d2; C[r][3] += d3;
      Cp[r][0] = fmaf(pm, d0, Cp[r][0]);
      Cp[r][1] = fmaf(pm, d1, Cp[r][1]);
      Cp[r][2] = fmaf(pm, d2, Cp[r][2]);
      Cp[r][3] = fmaf(pm, d3, Cp[r][3]);

      if (fabsf(a) > 0.4f) {   // rare (~1e-4): outlier or diagonal -> global atomics
        const int gRow = iRow[r];
        if (gRow == j) {
          // diagonal: cancel fast contributions and the bins>=7 base (+1)
          C[r][0] -= d0; C[r][1] -= d1; C[r][2] -= d2; C[r][3] -= d3;
          #pragma unroll
          for (int k = 7; k <= 10; ++k)
            atomicAdd(&gA[gRow * AROW + k], (unsigned)(-65536));
        } else {
          const float t = fmaf(a, -5.f, 5.f);
          #pragma unroll
          for (int k = 0; k <= 2; ++k) {         // assumed cumulative 0
            const float v = clamp01((float)(k + 1) - t);
            const int q = (int)(v * 65536.f + 0.5f);
            if (q) {
              atomicAdd(&gA[gRow * AROW + k], (unsigned)q);
              if (isPos) atomicAdd(&gAp[gRow * AROW + k], (unsigned)q);
            }
          }
          #pragma unroll
          for (int k = 7; k <= 10; ++k) {        // assumed cumulative 1
            const float v = clamp01((float)(k + 1) - t) - 1.f;
            const int q = (int)(v * 65536.f - 0.5f);
            if (q) {
              atomicAdd(&gA[gRow * AROW + k], (unsigned)q);
              if (isPos) atomicAdd(&gAp[gRow * AROW + k], (unsigned)q);
            }
          }
        }
      }
    }
  };

  stage(0, 0);
  __syncthreads();             // sLab visible + panel 0 drained (vmcnt(0))

  #pragma unroll 1
  for (int ph = 0; ph < NPH; ++ph) {
    const int cur = ph & 1;
    if (ph + 1 < NPH) stage(ph + 1, cur ^ 1);   // async DMA behind this phase
    const int base = ph * 64;
    tile16(&sB[cur][0 * 2048], base);
    tile16(&sB[cur][1 * 2048], base + 16);
    tile16(&sB[cur][2 * 2048], base + 32);
    tile16(&sB[cur][3 * 2048], base + 48);
    __syncthreads();           // all waves done with cur; next panel drained
  }

  // butterfly-reduce C/Cp across the 16 lanes sharing each row
  #pragma unroll
  for (int m = 1; m < 16; m <<= 1)
    #pragma unroll
    for (int r = 0; r < 4; ++r)
      #pragma unroll
      for (int k = 0; k < 4; ++k) {
        C[r][k]  += __shfl_xor(C[r][k],  m, 64);
        Cp[r][k] += __shfl_xor(Cp[r][k], m, 64);
      }

  if (l16 == 0) {
    #pragma unroll
    for (int r = 0; r < 4; ++r)
      #pragma unroll
      for (int k = 0; k < 4; ++k) {
        atomicAdd(&gS[(rowBase + rl0 + r) * 4 + k],  C[r][k]);
        atomicAdd(&gSp[(rowBase + rl0 + r) * 4 + k], Cp[r][k]);
      }
  }
}

// ---- epilogue: per-row AP + final loss (last block finalizes) ----
__global__ __launch_bounds__(256) void epilogue_kernel(
    const float* __restrict__ gS, const float* __restrict__ gSp,
    const unsigned* __restrict__ gA, const unsigned* __restrict__ gAp,
    const int* __restrict__ labels, const int* __restrict__ ccount,
    float* __restrict__ accum, unsigned* __restrict__ done,
    float* __restrict__ out) {
  const int i = blockIdx.x * 256 + threadIdx.x;
  const int np = ccount[labels[i]] - 1;   // N_pos = classCount - 1
  float ap = 0.f, val = 0.f, HpPrev = 0.f;
  #pragma unroll
  for (int b = 0; b <= 10; ++b) {
    const float baseH  = (b < 3) ? 0.f : (b < 7) ? gS[i * 4 + (b - 3)]  : 8192.f;
    const float basePp = (b < 3) ? 0.f : (b < 7) ? gSp[i * 4 + (b - 3)] : (float)np;
    const float H  = baseH  + (float)(int)gA[i * AROW + b]  * INV64K;
    const float Hp = basePp + (float)(int)gAp[i * AROW + b] * INV64K;
    const float hp = Hp - HpPrev;
    HpPrev = Hp;
    if (H > 1e-6f) ap += hp * Hp / H;
  }
  if (np > 0) { ap /= (float)np; val = 1.f; } else ap = 0.f;

  __shared__ float sa[256], sv[256];
  sa[threadIdx.x] = ap; sv[threadIdx.x] = val;
  __syncthreads();
  for (int s = 128; s > 0; s >>= 1) {
    if (threadIdx.x < s) {
      sa[threadIdx.x] += sa[threadIdx.x + s];
      sv[threadIdx.x] += sv[threadIdx.x + s];
    }
    __syncthreads();
  }
  if (threadIdx.x == 0) {
    atomicAdd(&accum[0], sa[0]);
    atomicAdd(&accum[1], sv[0]);
    __threadfence();
    const unsigned prev = atomicAdd(done, 1u);
    if (prev == gridDim.x - 1) {
      const float a = atomicAdd(&accum[0], 0.f);   // coherent reads
      const float c = atomicAdd(&accum[1], 0.f);
      out[0] = 1.f - (c > 0.f ? a / c : 0.f);
    }
  }
}

extern "C" void kernel_launch(void* const* d_in, const int* in_sizes, int n_in,
                              void* d_out, int out_size, void* d_ws, size_t ws_size,
                              hipStream_t stream) {
  const float* x      = (const float*)d_in[0];
  const int*   labels = (const int*)d_in[1];
  float* out = (float*)d_out;

  char* ws = (char*)d_ws;
  unsigned short* xb = (unsigned short*)(ws + OFF_XB);
  float*    gS   = (float*)(ws + OFF_GS);
  float*    gSp  = (float*)(ws + OFF_GSP);
  unsigned* gA   = (unsigned*)(ws + OFF_GA);
  unsigned* gAp  = (unsigned*)(ws + OFF_GAP);
  int*      cc   = (int*)(ws + OFF_CC);
  float*    accum = (float*)(ws + OFF_AC);
  unsigned* done  = (unsigned*)(ws + OFF_AC + 8);

  prep_kernel<<<512, 256, 0, stream>>>(x, xb, (uint4*)(ws + OFF_GS));
  fastap_main_kernel<<<dim3(NS / 64, NS / COLCHUNK), 256, 0, stream>>>(
      xb, labels, gS, gSp, gA, gAp, cc);
  epilogue_kernel<<<NS / 256, 256, 0, stream>>>(gS, gSp, gA, gAp, labels, cc,
                                                accum, done, out);
}

// Round 9
// 115.755 us; speedup vs baseline: 2.3755x; 1.3196x over previous
//
#include <hip/hip_runtime.h>

#define NS 8192
#define EMBED 128
#define ROWCHUNK 512             // grid.y = 16 chunks of 512 rows
#define NPANEL (ROWCHUNK / 32)   // 16 panels of 32 rows
#define AROW 12                  // correction-hist row stride (11 bins + 1 pad)
#define INV64K (1.0f / 65536.0f)

typedef __bf16 bf16x8 __attribute__((ext_vector_type(8)));
typedef float f32x4 __attribute__((ext_vector_type(4)));
typedef const __attribute__((address_space(1))) unsigned ag_u32;  // global
typedef __attribute__((address_space(3))) unsigned al_u32;        // LDS

// workspace layout (bytes from ws start)
#define OFF_XB  0u               // bf16 [8192][128] = 2 MiB (row-granule-XOR-swizzled)
#define OFF_GS  2097152u         // q16  [8192][4]   cumulative C bins 3..6
#define OFF_GSP 2228224u         // q16  [8192][4]   cumulative Cp bins 3..6
#define OFF_GA  2359296u         // q16  [8192][12]  all-hist corrections
#define OFF_GAP 2752512u         // q16  [8192][12]  pos-hist corrections
#define OFF_CC  3145728u         // int  [128] class counts
#define OFF_AC  3146240u         // float[2] accum + u32 done
#define ZERO_BYTES 1049120u      // OFF_GS .. end (16B multiple)

__device__ inline unsigned short f2bf(float f) {
  unsigned u = __float_as_uint(f);
  u += 0x7fffu + ((u >> 16) & 1u);   // round-to-nearest-even
  return (unsigned short)(u >> 16);
}
__device__ inline float clamp01(float x) { return __builtin_amdgcn_fmed3f(x, 0.f, 1.f); }

// ---- prep: fp32->bf16 convert into XOR-swizzled layout + zero accumulators ----
__global__ __launch_bounds__(256) void prep_kernel(const float* __restrict__ x,
                                                   unsigned short* __restrict__ xb,
                                                   uint4* __restrict__ zbase) {
  const int gid = blockIdx.x * 256 + threadIdx.x;   // 131072 threads: row*16+granule
  const int row = gid >> 4, g = gid & 15;
  const float4 v0 = reinterpret_cast<const float4*>(x)[row * 32 + g * 2];
  const float4 v1 = reinterpret_cast<const float4*>(x)[row * 32 + g * 2 + 1];
  uint4 o;
  o.x = (unsigned)f2bf(v0.x) | ((unsigned)f2bf(v0.y) << 16);
  o.y = (unsigned)f2bf(v0.z) | ((unsigned)f2bf(v0.w) << 16);
  o.z = (unsigned)f2bf(v1.x) | ((unsigned)f2bf(v1.y) << 16);
  o.w = (unsigned)f2bf(v1.z) | ((unsigned)f2bf(v1.w) << 16);
  reinterpret_cast<uint4*>(xb)[row * 16 + (g ^ (row & 7))] = o;
  if (gid < (int)(ZERO_BYTES / 16u)) zbase[gid] = make_uint4(0u, 0u, 0u, 0u);
}

// ---- main: fixed 16-col B frags per wave, streamed 32-row LDS panels ----
// Symmetry: per-row hist == per-col hist, so each lane accumulates the hist of
// ONE column (its l16 col) across all its 4 acc rows -> C[4]/Cp[4] registers.
__global__ __launch_bounds__(256, 8) void fastap_main_kernel(
    const unsigned short* __restrict__ xb,
    const int* __restrict__ labels,
    unsigned* __restrict__ gS, unsigned* __restrict__ gSp,
    unsigned* __restrict__ gA, unsigned* __restrict__ gAp,
    int* __restrict__ ccount) {
  __shared__ __align__(16) unsigned short sA[2][32 * 128];  // 2 x 8KB row panels
  __shared__ int sLab[ROWCHUNK];                            // this chunk's row labels

  const int tid  = threadIdx.x;
  const int wave = tid >> 6;
  const int lane = tid & 63;
  const int l16  = lane & 15;
  const int quad = lane >> 4;
  const int colBase  = blockIdx.x * 64;      // 128 col strips
  const int rowChunk = blockIdx.y * ROWCHUNK; // 16 row chunks

  if (tid < ROWCHUNK / 4)
    reinterpret_cast<int4*>(sLab)[tid] =
        reinterpret_cast<const int4*>(labels + rowChunk)[tid];

  // fixed B fragments: this wave's 16 cols, K=128 (jcol&7 == l16&7)
  const int jcol = colBase + wave * 16 + l16;
  bf16x8 bfr[4];
  #pragma unroll
  for (int kb = 0; kb < 4; ++kb) {
    const int pg = (kb * 4 + quad) ^ (l16 & 7);
    bfr[kb] = *reinterpret_cast<const bf16x8*>(&xb[jcol * 128 + pg * 8]);
  }
  const int labj = labels[jcol];

  float C[4] = {0.f, 0.f, 0.f, 0.f}, Cp[4] = {0.f, 0.f, 0.f, 0.f};

  // A-frag ds_read offsets within a 16-row sub-panel (row&7 == l16&7)
  int aOff[4];
  #pragma unroll
  for (int kb = 0; kb < 4; ++kb)
    aOff[kb] = l16 * 128 + (((kb * 4 + quad) ^ (l16 & 7)) << 3);

  // stage panel p's 32 rows (8KB) into buffer b: 2 x 16B per thread
  const unsigned short* xrb = xb + rowChunk * 128;
  auto stage = [&](int p, int b) {
    const unsigned short* src = xrb + p * (32 * 128);
    __builtin_amdgcn_global_load_lds((ag_u32*)(src + tid * 8),
                                     (al_u32*)(&sA[b][tid * 8]), 16, 0, 0);
    __builtin_amdgcn_global_load_lds((ag_u32*)(src + (tid + 256) * 8),
                                     (al_u32*)(&sA[b][(tid + 256) * 8]), 16, 0, 0);
  };

  // one 16-row x 16-col tile; lcr = row offset within chunk (mult of 16)
  auto tile16 = [&](const unsigned short* ap, int lcr) {
    const int4 lr = *reinterpret_cast<const int4*>(&sLab[lcr + quad * 4]);
    bf16x8 a0 = *reinterpret_cast<const bf16x8*>(&ap[aOff[0]]);
    bf16x8 a1 = *reinterpret_cast<const bf16x8*>(&ap[aOff[1]]);
    bf16x8 a2 = *reinterpret_cast<const bf16x8*>(&ap[aOff[2]]);
    bf16x8 a3 = *reinterpret_cast<const bf16x8*>(&ap[aOff[3]]);
    f32x4 acc0 = {0.f, 0.f, 0.f, 0.f}, acc1 = {0.f, 0.f, 0.f, 0.f};
    acc0 = __builtin_amdgcn_mfma_f32_16x16x32_bf16(a0, bfr[0], acc0, 0, 0, 0);
    acc0 = __builtin_amdgcn_mfma_f32_16x16x32_bf16(a1, bfr[1], acc0, 0, 0, 0);
    acc1 = __builtin_amdgcn_mfma_f32_16x16x32_bf16(a2, bfr[2], acc1, 0, 0, 0);
    acc1 = __builtin_amdgcn_mfma_f32_16x16x32_bf16(a3, bfr[3], acc1, 0, 0, 0);

    const int labr[4] = {lr.x, lr.y, lr.z, lr.w};
    #pragma unroll
    for (int r = 0; r < 4; ++r) {              // D: row = quad*4+r, col = l16
      const float a = acc0[r] + acc1[r];       // cos(i, jcol)
      const float pm = (labr[r] == labj) ? 1.f : 0.f;   // diag corrected in rare path
      const float d0 = clamp01(fmaf(a, 5.f, -1.f));   // bin 3
      const float d1 = clamp01(a * 5.f);              // bin 4
      const float d2 = clamp01(fmaf(a, 5.f, 1.f));    // bin 5
      const float d3 = clamp01(fmaf(a, 5.f, 2.f));    // bin 6
      C[0] += d0; C[1] += d1; C[2] += d2; C[3] += d3;
      Cp[0] = fmaf(pm, d0, Cp[0]);
      Cp[1] = fmaf(pm, d1, Cp[1]);
      Cp[2] = fmaf(pm, d2, Cp[2]);
      Cp[3] = fmaf(pm, d3, Cp[3]);

      if (fabsf(a) > 0.4f) {   // rare (~1e-5): outlier or the diagonal
        const int i = rowChunk + lcr + quad * 4 + r;
        if (i == jcol) {
          // diagonal: cancel fast contributions (pm was 1) + bins>=7 base (+1)
          C[0] -= d0; C[1] -= d1; C[2] -= d2; C[3] -= d3;
          Cp[0] -= d0; Cp[1] -= d1; Cp[2] -= d2; Cp[3] -= d3;
          #pragma unroll
          for (int k = 7; k <= 10; ++k)
            atomicAdd(&gA[jcol * AROW + k], (unsigned)(-65536));
        } else {
          const bool isPos = (labr[r] == labj);
          const float t = fmaf(a, -5.f, 5.f);
          #pragma unroll
          for (int k = 0; k <= 2; ++k) {       // assumed cumulative 0
            const float v = clamp01((float)(k + 1) - t);
            const int q = (int)(v * 65536.f + 0.5f);
            if (q) {
              atomicAdd(&gA[jcol * AROW + k], (unsigned)q);
              if (isPos) atomicAdd(&gAp[jcol * AROW + k], (unsigned)q);
            }
          }
          #pragma unroll
          for (int k = 7; k <= 10; ++k) {      // assumed cumulative 1
            const float v = clamp01((float)(k + 1) - t) - 1.f;
            const int q = (int)(v * 65536.f - 0.5f);
            if (q) {
              atomicAdd(&gA[jcol * AROW + k], (unsigned)q);
              if (isPos) atomicAdd(&gAp[jcol * AROW + k], (unsigned)q);
            }
          }
        }
      }
    }
  };

  stage(0, 0);
  __syncthreads();             // sLab visible + panel 0 drained

  // class counts: one col-strip per row-chunk counts its 512 rows
  if (blockIdx.x == 0) {
    for (int idx = tid; idx < ROWCHUNK; idx += 256)
      atomicAdd(&ccount[sLab[idx]], 1);
  }

  #pragma unroll 1
  for (int p = 0; p < NPANEL; ++p) {
    const int cur = p & 1;
    if (p + 1 < NPANEL) stage(p + 1, cur ^ 1);   // async DMA behind this panel
    tile16(&sA[cur][0],        p * 32);
    tile16(&sA[cur][16 * 128], p * 32 + 16);
    __syncthreads();
  }

  // reduce across the 4 quads sharing each column (lane ^16, ^32)
  #pragma unroll
  for (int m = 16; m < 64; m <<= 1)
    #pragma unroll
    for (int k = 0; k < 4; ++k) {
      C[k]  += __shfl_xor(C[k],  m, 64);
      Cp[k] += __shfl_xor(Cp[k], m, 64);
    }

  if (quad == 0) {
    #pragma unroll
    for (int k = 0; k < 4; ++k) {
      atomicAdd(&gS[jcol * 4 + k],  (unsigned)(int)lrintf(C[k]  * 65536.f));
      atomicAdd(&gSp[jcol * 4 + k], (unsigned)(int)lrintf(Cp[k] * 65536.f));
    }
  }
}

// ---- epilogue: per-row AP + final loss (last block finalizes) ----
__global__ __launch_bounds__(256) void epilogue_kernel(
    const unsigned* __restrict__ gS, const unsigned* __restrict__ gSp,
    const unsigned* __restrict__ gA, const unsigned* __restrict__ gAp,
    const int* __restrict__ labels, const int* __restrict__ ccount,
    float* __restrict__ accum, unsigned* __restrict__ done,
    float* __restrict__ out) {
  const int i = blockIdx.x * 256 + threadIdx.x;
  const int np = ccount[labels[i]] - 1;   // N_pos = classCount - 1
  float ap = 0.f, val = 0.f, HpPrev = 0.f;
  #pragma unroll
  for (int b = 0; b <= 10; ++b) {
    const float baseH  = (b < 3) ? 0.f
                       : (b < 7) ? (float)(int)gS[i * 4 + (b - 3)]  * INV64K : 8192.f;
    const float basePp = (b < 3) ? 0.f
                       : (b < 7) ? (float)(int)gSp[i * 4 + (b - 3)] * INV64K : (float)np;
    const float H  = baseH  + (float)(int)gA[i * AROW + b]  * INV64K;
    const float Hp = basePp + (float)(int)gAp[i * AROW + b] * INV64K;
    const float hp = Hp - HpPrev;
    HpPrev = Hp;
    if (H > 1e-6f) ap += hp * Hp / H;
  }
  if (np > 0) { ap /= (float)np; val = 1.f; } else ap = 0.f;

  __shared__ float sa[256], sv[256];
  sa[threadIdx.x] = ap; sv[threadIdx.x] = val;
  __syncthreads();
  for (int s = 128; s > 0; s >>= 1) {
    if (threadIdx.x < s) {
      sa[threadIdx.x] += sa[threadIdx.x + s];
      sv[threadIdx.x] += sv[threadIdx.x + s];
    }
    __syncthreads();
  }
  if (threadIdx.x == 0) {
    atomicAdd(&accum[0], sa[0]);
    atomicAdd(&accum[1], sv[0]);
    __threadfence();
    const unsigned prev = atomicAdd(done, 1u);
    if (prev == gridDim.x - 1) {
      const float a = atomicAdd(&accum[0], 0.f);   // coherent reads
      const float c = atomicAdd(&accum[1], 0.f);
      out[0] = 1.f - (c > 0.f ? a / c : 0.f);
    }
  }
}

extern "C" void kernel_launch(void* const* d_in, const int* in_sizes, int n_in,
                              void* d_out, int out_size, void* d_ws, size_t ws_size,
                              hipStream_t stream) {
  const float* x      = (const float*)d_in[0];
  const int*   labels = (const int*)d_in[1];
  float* out = (float*)d_out;

  char* ws = (char*)d_ws;
  unsigned short* xb = (unsigned short*)(ws + OFF_XB);
  unsigned* gS   = (unsigned*)(ws + OFF_GS);
  unsigned* gSp  = (unsigned*)(ws + OFF_GSP);
  unsigned* gA   = (unsigned*)(ws + OFF_GA);
  unsigned* gAp  = (unsigned*)(ws + OFF_GAP);
  int*      cc   = (int*)(ws + OFF_CC);
  float*    accum = (float*)(ws + OFF_AC);
  unsigned* done  = (unsigned*)(ws + OFF_AC + 8);

  prep_kernel<<<512, 256, 0, stream>>>(x, xb, (uint4*)(ws + OFF_GS));
  fastap_main_kernel<<<dim3(NS / 64, NS / ROWCHUNK), 256, 0, stream>>>(
      xb, labels, gS, gSp, gA, gAp, cc);
  epilogue_kernel<<<NS / 256, 256, 0, stream>>>(gS, gSp, gA, gAp, labels, cc,
                                                accum, done, out);
}

// Round 10
// 113.379 us; speedup vs baseline: 2.4253x; 1.0210x over previous
//
#include <hip/hip_runtime.h>

#define NS 8192
#define EMBED 128
#define ROWCHUNK 512             // grid.y = 16 chunks of 512 rows
#define NPANEL (ROWCHUNK / 32)   // 16 panels of 32 rows
#define AROW 12                  // correction-hist row stride (11 bins + 1 pad)
#define INV64K (1.0f / 65536.0f)

typedef __bf16 bf16x8 __attribute__((ext_vector_type(8)));
typedef float f32x4 __attribute__((ext_vector_type(4)));
typedef float f32x2 __attribute__((ext_vector_type(2)));
typedef const __attribute__((address_space(1))) unsigned ag_u32;  // global
typedef __attribute__((address_space(3))) unsigned al_u32;        // LDS

// workspace layout (bytes from ws start)
#define OFF_XB  0u               // bf16 [8192][128] = 2 MiB (row-granule-XOR-swizzled)
#define OFF_GS  2097152u         // q16  [8192][4]   cumulative C bins 3..6
#define OFF_GSP 2228224u         // q16  [8192][4]   cumulative Cp bins 3..6
#define OFF_GA  2359296u         // q16  [8192][12]  all-hist corrections
#define OFF_GAP 2752512u         // q16  [8192][12]  pos-hist corrections
#define OFF_CC  3145728u         // int  [128] class counts
#define OFF_AC  3146240u         // float[2] accum + u32 done
#define ZERO_BYTES 1049120u      // OFF_GS .. end (16B multiple)

__device__ inline unsigned short f2bf(float f) {
  unsigned u = __float_as_uint(f);
  u += 0x7fffu + ((u >> 16) & 1u);   // round-to-nearest-even
  return (unsigned short)(u >> 16);
}
__device__ inline float clamp01(float x) { return __builtin_amdgcn_fmed3f(x, 0.f, 1.f); }
__device__ inline f32x2 pkclamp01(f32x2 v) {
  return __builtin_elementwise_min(__builtin_elementwise_max(v, (f32x2){0.f, 0.f}),
                                   (f32x2){1.f, 1.f});
}

// ---- prep: fp32->bf16 convert into XOR-swizzled layout + zero accumulators ----
__global__ __launch_bounds__(256) void prep_kernel(const float* __restrict__ x,
                                                   unsigned short* __restrict__ xb,
                                                   uint4* __restrict__ zbase) {
  const int gid = blockIdx.x * 256 + threadIdx.x;   // 131072 threads: row*16+granule
  const int row = gid >> 4, g = gid & 15;
  const float4 v0 = reinterpret_cast<const float4*>(x)[row * 32 + g * 2];
  const float4 v1 = reinterpret_cast<const float4*>(x)[row * 32 + g * 2 + 1];
  uint4 o;
  o.x = (unsigned)f2bf(v0.x) | ((unsigned)f2bf(v0.y) << 16);
  o.y = (unsigned)f2bf(v0.z) | ((unsigned)f2bf(v0.w) << 16);
  o.z = (unsigned)f2bf(v1.x) | ((unsigned)f2bf(v1.y) << 16);
  o.w = (unsigned)f2bf(v1.z) | ((unsigned)f2bf(v1.w) << 16);
  reinterpret_cast<uint4*>(xb)[row * 16 + (g ^ (row & 7))] = o;
  if (gid < (int)(ZERO_BYTES / 16u)) zbase[gid] = make_uint4(0u, 0u, 0u, 0u);
}

// ---- main: fixed 16-col B frags per wave, streamed 32-row LDS panels ----
// Symmetry: per-row hist == per-col hist, so each lane accumulates the hist of
// ONE column (its l16 col) across its 4 acc rows -> packed C01/C23, Cp01/Cp23.
__global__ __launch_bounds__(256, 8) void fastap_main_kernel(
    const unsigned short* __restrict__ xb,
    const int* __restrict__ labels,
    unsigned* __restrict__ gS, unsigned* __restrict__ gSp,
    unsigned* __restrict__ gA, unsigned* __restrict__ gAp,
    int* __restrict__ ccount) {
  __shared__ __align__(16) unsigned short sA[2][32 * 128];  // 2 x 8KB row panels
  __shared__ int sLab[ROWCHUNK];                            // this chunk's row labels

  const int tid  = threadIdx.x;
  const int wave = tid >> 6;
  const int lane = tid & 63;
  const int l16  = lane & 15;
  const int quad = lane >> 4;
  const int colBase  = blockIdx.x * 64;       // 128 col strips
  const int rowChunk = blockIdx.y * ROWCHUNK; // 16 row chunks

  if (tid < ROWCHUNK / 4)
    reinterpret_cast<int4*>(sLab)[tid] =
        reinterpret_cast<const int4*>(labels + rowChunk)[tid];

  // fixed B fragments: this wave's 16 cols, K=128 (jcol&7 == l16&7)
  const int jcol = colBase + wave * 16 + l16;
  bf16x8 bfr[4];
  #pragma unroll
  for (int kb = 0; kb < 4; ++kb) {
    const int pg = (kb * 4 + quad) ^ (l16 & 7);
    bfr[kb] = *reinterpret_cast<const bf16x8*>(&xb[jcol * 128 + pg * 8]);
  }
  const int labj = labels[jcol];

  f32x2 C01 = {0.f, 0.f}, C23 = {0.f, 0.f};
  f32x2 Cp01 = {0.f, 0.f}, Cp23 = {0.f, 0.f};

  // A-frag ds_read offsets within a 16-row sub-panel (row&7 == l16&7)
  int aOff[4];
  #pragma unroll
  for (int kb = 0; kb < 4; ++kb)
    aOff[kb] = l16 * 128 + (((kb * 4 + quad) ^ (l16 & 7)) << 3);

  // stage panel p's 32 rows (8KB) into buffer b: 2 x 16B per thread
  const unsigned short* xrb = xb + rowChunk * 128;
  auto stage = [&](int p, int b) {
    const unsigned short* src = xrb + p * (32 * 128);
    __builtin_amdgcn_global_load_lds((ag_u32*)(src + tid * 8),
                                     (al_u32*)(&sA[b][tid * 8]), 16, 0, 0);
    __builtin_amdgcn_global_load_lds((ag_u32*)(src + (tid + 256) * 8),
                                     (al_u32*)(&sA[b][(tid + 256) * 8]), 16, 0, 0);
  };

  // one 16-row x 16-col tile; lcr = row offset within chunk (mult of 16)
  auto tile16 = [&](const unsigned short* ap, int lcr) {
    const int4 lr = *reinterpret_cast<const int4*>(&sLab[lcr + quad * 4]);
    bf16x8 a0 = *reinterpret_cast<const bf16x8*>(&ap[aOff[0]]);
    bf16x8 a1 = *reinterpret_cast<const bf16x8*>(&ap[aOff[1]]);
    bf16x8 a2 = *reinterpret_cast<const bf16x8*>(&ap[aOff[2]]);
    bf16x8 a3 = *reinterpret_cast<const bf16x8*>(&ap[aOff[3]]);
    f32x4 acc = {0.f, 0.f, 0.f, 0.f};    // single chain: 8 waves/SIMD hide latency
    acc = __builtin_amdgcn_mfma_f32_16x16x32_bf16(a0, bfr[0], acc, 0, 0, 0);
    acc = __builtin_amdgcn_mfma_f32_16x16x32_bf16(a1, bfr[1], acc, 0, 0, 0);
    acc = __builtin_amdgcn_mfma_f32_16x16x32_bf16(a2, bfr[2], acc, 0, 0, 0);
    acc = __builtin_amdgcn_mfma_f32_16x16x32_bf16(a3, bfr[3], acc, 0, 0, 0);

    const int labr[4] = {lr.x, lr.y, lr.z, lr.w};
    // fast path: packed f32 (v_pk_fma/min/max). Register bins 3..6 are EXACT
    // for all t: H[k] = clamp01(5a + (k-4)).
    #pragma unroll
    for (int r = 0; r < 4; ++r) {              // D: row = quad*4+r, col = l16
      const float a = acc[r];                  // cos(i, jcol)
      const float pm = (labr[r] == labj) ? 1.f : 0.f;  // diag fixed in rare path
      const f32x2 av = {a, a}, p2 = {pm, pm};
      const f32x2 d01 = pkclamp01(__builtin_elementwise_fma(av, (f32x2){5.f, 5.f},
                                                            (f32x2){-1.f, 0.f}));
      const f32x2 d23 = pkclamp01(__builtin_elementwise_fma(av, (f32x2){5.f, 5.f},
                                                            (f32x2){1.f, 2.f}));
      C01 += d01; C23 += d23;
      Cp01 = __builtin_elementwise_fma(p2, d01, Cp01);
      Cp23 = __builtin_elementwise_fma(p2, d23, Cp23);
    }

    // one rare check per 4 pairs (abs modifiers are free on v_max)
    const float mabs = fmaxf(fmaxf(fabsf(acc[0]), fabsf(acc[1])),
                             fmaxf(fabsf(acc[2]), fabsf(acc[3])));
    if (__builtin_expect(mabs > 0.4f, 0)) {
      #pragma unroll
      for (int r = 0; r < 4; ++r) {
        const float a = acc[r];
        if (fabsf(a) <= 0.4f) continue;
        const int i = rowChunk + lcr + quad * 4 + r;
        // recompute (bit-identical to fast path)
        const float d0 = clamp01(fmaf(a, 5.f, -1.f));
        const float d1 = clamp01(a * 5.f);
        const float d2 = clamp01(fmaf(a, 5.f, 1.f));
        const float d3 = clamp01(fmaf(a, 5.f, 2.f));
        if (i == jcol) {
          // diagonal: cancel fast contributions (pm was 1) + bins>=7 base (+1)
          C01 -= (f32x2){d0, d1};  C23 -= (f32x2){d2, d3};
          Cp01 -= (f32x2){d0, d1}; Cp23 -= (f32x2){d2, d3};
          #pragma unroll
          for (int k = 7; k <= 10; ++k)
            atomicAdd(&gA[jcol * AROW + k], (unsigned)(-65536));
        } else {
          const bool isPos = (labr[r] == labj);
          const float t = fmaf(a, -5.f, 5.f);
          #pragma unroll
          for (int k = 0; k <= 2; ++k) {       // assumed cumulative 0
            const float v = clamp01((float)(k + 1) - t);
            const int q = (int)(v * 65536.f + 0.5f);
            if (q) {
              atomicAdd(&gA[jcol * AROW + k], (unsigned)q);
              if (isPos) atomicAdd(&gAp[jcol * AROW + k], (unsigned)q);
            }
          }
          #pragma unroll
          for (int k = 7; k <= 10; ++k) {      // assumed cumulative 1
            const float v = clamp01((float)(k + 1) - t) - 1.f;
            const int q = (int)(v * 65536.f - 0.5f);
            if (q) {
              atomicAdd(&gA[jcol * AROW + k], (unsigned)q);
              if (isPos) atomicAdd(&gAp[jcol * AROW + k], (unsigned)q);
            }
          }
        }
      }
    }
  };

  stage(0, 0);
  __syncthreads();             // sLab visible + panel 0 drained

  // class counts: one col-strip per row-chunk counts its 512 rows
  if (blockIdx.x == 0) {
    for (int idx = tid; idx < ROWCHUNK; idx += 256)
      atomicAdd(&ccount[sLab[idx]], 1);
  }

  #pragma unroll 1
  for (int p = 0; p < NPANEL; ++p) {
    const int cur = p & 1;
    if (p + 1 < NPANEL) stage(p + 1, cur ^ 1);   // async DMA behind this panel
    tile16(&sA[cur][0],        p * 32);
    tile16(&sA[cur][16 * 128], p * 32 + 16);
    __syncthreads();
  }

  // reduce across the 4 quads sharing each column (lane ^16, ^32)
  #pragma unroll
  for (int m = 16; m < 64; m <<= 1) {
    C01.x  += __shfl_xor(C01.x,  m, 64); C01.y  += __shfl_xor(C01.y,  m, 64);
    C23.x  += __shfl_xor(C23.x,  m, 64); C23.y  += __shfl_xor(C23.y,  m, 64);
    Cp01.x += __shfl_xor(Cp01.x, m, 64); Cp01.y += __shfl_xor(Cp01.y, m, 64);
    Cp23.x += __shfl_xor(Cp23.x, m, 64); Cp23.y += __shfl_xor(Cp23.y, m, 64);
  }

  if (quad == 0) {
    const float Cv[4]  = {C01.x, C01.y, C23.x, C23.y};
    const float Cpv[4] = {Cp01.x, Cp01.y, Cp23.x, Cp23.y};
    #pragma unroll
    for (int k = 0; k < 4; ++k) {
      atomicAdd(&gS[jcol * 4 + k],  (unsigned)(int)lrintf(Cv[k]  * 65536.f));
      atomicAdd(&gSp[jcol * 4 + k], (unsigned)(int)lrintf(Cpv[k] * 65536.f));
    }
  }
}

// ---- epilogue: per-row AP + final loss (last block finalizes) ----
__global__ __launch_bounds__(256) void epilogue_kernel(
    const unsigned* __restrict__ gS, const unsigned* __restrict__ gSp,
    const unsigned* __restrict__ gA, const unsigned* __restrict__ gAp,
    const int* __restrict__ labels, const int* __restrict__ ccount,
    float* __restrict__ accum, unsigned* __restrict__ done,
    float* __restrict__ out) {
  const int i = blockIdx.x * 256 + threadIdx.x;
  const int np = ccount[labels[i]] - 1;   // N_pos = classCount - 1
  float ap = 0.f, val = 0.f, HpPrev = 0.f;
  #pragma unroll
  for (int b = 0; b <= 10; ++b) {
    const float baseH  = (b < 3) ? 0.f
                       : (b < 7) ? (float)(int)gS[i * 4 + (b - 3)]  * INV64K : 8192.f;
    const float basePp = (b < 3) ? 0.f
                       : (b < 7) ? (float)(int)gSp[i * 4 + (b - 3)] * INV64K : (float)np;
    const float H  = baseH  + (float)(int)gA[i * AROW + b]  * INV64K;
    const float Hp = basePp + (float)(int)gAp[i * AROW + b] * INV64K;
    const float hp = Hp - HpPrev;
    HpPrev = Hp;
    if (H > 1e-6f) ap += hp * Hp / H;
  }
  if (np > 0) { ap /= (float)np; val = 1.f; } else ap = 0.f;

  __shared__ float sa[256], sv[256];
  sa[threadIdx.x] = ap; sv[threadIdx.x] = val;
  __syncthreads();
  for (int s = 128; s > 0; s >>= 1) {
    if (threadIdx.x < s) {
      sa[threadIdx.x] += sa[threadIdx.x + s];
      sv[threadIdx.x] += sv[threadIdx.x + s];
    }
    __syncthreads();
  }
  if (threadIdx.x == 0) {
    atomicAdd(&accum[0], sa[0]);
    atomicAdd(&accum[1], sv[0]);
    __threadfence();
    const unsigned prev = atomicAdd(done, 1u);
    if (prev == gridDim.x - 1) {
      const float a = atomicAdd(&accum[0], 0.f);   // coherent reads
      const float c = atomicAdd(&accum[1], 0.f);
      out[0] = 1.f - (c > 0.f ? a / c : 0.f);
    }
  }
}

extern "C" void kernel_launch(void* const* d_in, const int* in_sizes, int n_in,
                              void* d_out, int out_size, void* d_ws, size_t ws_size,
                              hipStream_t stream) {
  const float* x      = (const float*)d_in[0];
  const int*   labels = (const int*)d_in[1];
  float* out = (float*)d_out;

  char* ws = (char*)d_ws;
  unsigned short* xb = (unsigned short*)(ws + OFF_XB);
  unsigned* gS   = (unsigned*)(ws + OFF_GS);
  unsigned* gSp  = (unsigned*)(ws + OFF_GSP);
  unsigned* gA   = (unsigned*)(ws + OFF_GA);
  unsigned* gAp  = (unsigned*)(ws + OFF_GAP);
  int*      cc   = (int*)(ws + OFF_CC);
  float*    accum = (float*)(ws + OFF_AC);
  unsigned* done  = (unsigned*)(ws + OFF_AC + 8);

  prep_kernel<<<512, 256, 0, stream>>>(x, xb, (uint4*)(ws + OFF_GS));
  fastap_main_kernel<<<dim3(NS / 64, NS / ROWCHUNK), 256, 0, stream>>>(
      xb, labels, gS, gSp, gA, gAp, cc);
  epilogue_kernel<<<NS / 256, 256, 0, stream>>>(gS, gSp, gA, gAp, labels, cc,
                                                accum, done, out);
}